// Round 1
// 322.182 us; speedup vs baseline: 1.0176x; 1.0176x over previous
//
#include <hip/hip_runtime.h>
#include <hip/hip_bf16.h>
#include <math.h>

#define Mdim 2048
#define FD   128

// LDS map (bytes) — double-buffered B tile + merge/refine scratch
#define OFF_B0   0
#define OFF_B1   32768
#define OFF_FVAL 65536      // double[64][9] = 4608
#define OFF_FIDX 70144      // int[64][9]    = 2304
#define SMEM_SZ  72448      // <= 81920 -> 2 blocks/CU (grid is 2/CU anyway)

typedef __attribute__((ext_vector_type(8))) short short8;
typedef __attribute__((ext_vector_type(4))) float f32x4;

// ---------- pack float -> monotone u32 key | 11-bit col index ----------
__device__ __forceinline__ unsigned pkey(float v, int n) {
    unsigned u = __float_as_uint(v);
    unsigned mk = u ^ ((unsigned)((int)u >> 31) | 0x80000000u);
    return (mk & 0xFFFFF800u) | (unsigned)n;
}

// inverse of pkey's value bits, floored to the 21-bit quantum.
// Gate uses fm >= floor(thr) which is a superset of the packed gate.
__device__ __forceinline__ float unpack_floor(unsigned k) {
    unsigned vb = k & 0xFFFFF800u;
    unsigned u = (vb & 0x80000000u) ? (vb ^ 0x80000000u) : ~vb;
    return __uint_as_float(u);
}

// branchless sorted-desc top-3 insert on packed keys
__device__ __forceinline__ void ins3p(unsigned k, unsigned t[3]) {
    bool g2 = k > t[2], g1 = k > t[1], g0 = k > t[0];
    t[2] = g1 ? t[1] : (g2 ? k : t[2]);
    t[1] = g0 ? t[0] : (g1 ? k : t[1]);
    t[0] = g0 ? k : t[0];
}

// sorted-desc top-8 insert with early-out (merge phase, packed keys)
__device__ __forceinline__ void ins8p(unsigned k, unsigned bv[8]) {
    if (k <= bv[7]) return;
    #pragma unroll
    for (int s = 0; s < 8; ++s) {
        if (k > bv[s]) { unsigned o = bv[s]; bv[s] = k; k = o; }
    }
}

// ---------- Kernel 1: fp64 norms + normalized bf16 copy, chunk-swizzled ----------
// xnb row r, physical 16B-chunk p holds logical chunk j = p ^ (r & 15).
__global__ void prep_kernel(const float* __restrict__ x,
                            double* __restrict__ nrm_d,
                            unsigned short* __restrict__ xnb) {
    __shared__ unsigned short sb[4][128];
    int w = threadIdx.x >> 6, lane = threadIdx.x & 63;
    int row = blockIdx.x * 4 + w;
    const float* p = x + (size_t)row * FD;
    float v0 = p[lane], v1 = p[lane + 64];
    double d = (double)v0 * (double)v0 + (double)v1 * (double)v1;
    #pragma unroll
    for (int off = 32; off; off >>= 1) d += __shfl_down(d, off);
    d = __shfl(d, 0);
    double nrm = fmax(sqrt(d), 1e-12);
    if (lane == 0) nrm_d[row] = nrm;
    double inv = 1.0 / nrm;
    __hip_bfloat16 ha = __float2bfloat16((float)((double)v0 * inv));
    __hip_bfloat16 hb = __float2bfloat16((float)((double)v1 * inv));
    sb[w][lane]      = *reinterpret_cast<unsigned short*>(&ha);
    sb[w][lane + 64] = *reinterpret_cast<unsigned short*>(&hb);
    __syncthreads();
    if (lane < 16) {
        int j = lane ^ (row & 15);   // logical chunk stored at physical 'lane'
        short8 v = *(const short8*)&sb[w][j * 8];
        *(short8*)(xnb + (size_t)row * FD + lane * 8) = v;
    }
}

// ---------- Kernel 2: MFMA GEMM + packed top-k + fp64 refine + dense write ----------
__launch_bounds__(256, 2)
__global__ void topk_kernel(const float* __restrict__ x,
                            const unsigned short* __restrict__ xnb,
                            const double* __restrict__ nrm_d,
                            float* __restrict__ out,
                            int2* __restrict__ tops_i,
                            float2* __restrict__ tops_v) {
    __shared__ __align__(16) char smem[SMEM_SZ];

    int b  = blockIdx.x >> 5;
    int rt = blockIdx.x & 31;
    int row0 = rt * 64;
    const unsigned short* xb = xnb + (size_t)b * Mdim * FD;

    int tid  = threadIdx.x;
    int lane = tid & 63;
    int w    = tid >> 6;
    int wy   = w >> 1, wx = w & 1;     // wave tile: 32 rows x 64 cols
    int c    = lane & 15, q = lane >> 4;

    // A fragments (global chunks swizzled by row)
    short8 afr[2][4];
    #pragma unroll
    for (int rs = 0; rs < 2; ++rs)
        #pragma unroll
        for (int s = 0; s < 4; ++s) {
            int row = row0 + wy*32 + rs*16 + c;
            int p = ((s << 2) + q) ^ (row & 15);
            afr[rs][s] = *(const short8*)(xb + (size_t)row * FD + p * 8);
        }

    // per-lane packed top-3 per owned row (8 rows/lane) + float floor cache
    unsigned tvp[8][3];
    float    fthr[8];
    #pragma unroll
    for (int i = 0; i < 8; ++i) {
        tvp[i][0] = 0; tvp[i][1] = 0; tvp[i][2] = 0;
        fthr[i] = -1e30f;
    }

    float* zbase = out + (size_t)b * Mdim * Mdim
                 + (size_t)(row0 + (tid >> 5)) * Mdim + (tid & 31) * 4;

    // ---- prologue: stage chunk 0 into buf0, drain once ----
    {
        #pragma unroll
        for (int i = 0; i < 8; ++i) {
            const void* gp = xb + (size_t)(w*32 + i*4 + (lane >> 4)) * FD
                           + (lane & 15) * 8;
            void* lp = smem + OFF_B0 + ((w*32 + i*4) * 128) * sizeof(unsigned short);
            __builtin_amdgcn_global_load_lds(
                (const __attribute__((address_space(1))) unsigned*)gp,
                (__attribute__((address_space(3))) unsigned*)lp, 16, 0, 0);
        }
    }
    __syncthreads();

    #pragma unroll 1
    for (int ch = 0; ch < Mdim / 128; ++ch) {
        int col0 = ch * 128;
        unsigned short* Bcur = (unsigned short*)(smem + ((ch & 1) ? OFF_B1 : OFF_B0));

        // stage NEXT chunk into the other buffer (overlaps with compute below)
        if (ch + 1 < Mdim / 128) {
            char* Bnxt = smem + ((ch & 1) ? OFF_B0 : OFF_B1);
            int ncol0 = col0 + 128;
            #pragma unroll
            for (int i = 0; i < 8; ++i) {
                const void* gp = xb + (size_t)(ncol0 + w*32 + i*4 + (lane >> 4)) * FD
                               + (lane & 15) * 8;
                void* lp = Bnxt + ((w*32 + i*4) * 128) * sizeof(unsigned short);
                __builtin_amdgcn_global_load_lds(
                    (const __attribute__((address_space(1))) unsigned*)gp,
                    (__attribute__((address_space(3))) unsigned*)lp, 16, 0, 0);
            }
        }

        // zero-write this chunk's output slice (independent; overlaps MFMA)
        {
            float4 z = make_float4(0.f, 0.f, 0.f, 0.f);
            #pragma unroll
            for (int t = 0; t < 8; ++t)
                *(float4*)(zbase + (size_t)t * 8 * Mdim) = z;
            zbase += 128;
        }

        f32x4 acc[2][4];
        #pragma unroll
        for (int rs = 0; rs < 2; ++rs)
            #pragma unroll
            for (int ct = 0; ct < 4; ++ct)
                acc[rs][ct] = (f32x4){0.f, 0.f, 0.f, 0.f};

        #pragma unroll
        for (int s = 0; s < 4; ++s)
            #pragma unroll
            for (int ct = 0; ct < 4; ++ct) {
                int p = ((s << 2) + q) ^ c;   // swizzle key = col & 15 = c
                short8 bfr = *(const short8*)(Bcur + (size_t)(wx*64 + ct*16 + c) * 128 + p * 8);
                acc[0][ct] = __builtin_amdgcn_mfma_f32_16x16x32_bf16(afr[0][s], bfr, acc[0][ct], 0, 0, 0);
                acc[1][ct] = __builtin_amdgcn_mfma_f32_16x16x32_bf16(afr[1][s], bfr, acc[1][ct], 0, 0, 0);
            }

        // scan: cheap float gate first, packed keys only when it passes
        int nbase = col0 + wx*64 + c;
        #pragma unroll
        for (int rs = 0; rs < 2; ++rs)
            #pragma unroll
            for (int i = 0; i < 4; ++i) {
                int rr = rs*4 + i;
                float f0 = acc[rs][0][i], f1 = acc[rs][1][i];
                float f2 = acc[rs][2][i], f3 = acc[rs][3][i];
                float fm = fmaxf(fmaxf(f0, f1), fmaxf(f2, f3));
                if (fm >= fthr[rr]) {
                    ins3p(pkey(f0, nbase),      tvp[rr]);
                    ins3p(pkey(f1, nbase + 16), tvp[rr]);
                    ins3p(pkey(f2, nbase + 32), tvp[rr]);
                    ins3p(pkey(f3, nbase + 48), tvp[rr]);
                    fthr[rr] = unpack_floor(tvp[rr][2]);
                }
            }

        // single barrier per chunk: its vmcnt(0) drains the NEXT-chunk loads
        // (issued at iteration top -> latency hidden under compute) and
        // fences buf reuse across waves.
        __syncthreads();
    }

    // ---- merge: per-lane top-3 -> per-row pool of 96 packed keys ----
    __syncthreads();
    unsigned* mpool = (unsigned*)smem;      // [64][97], reuses buf0
    {
        int slot = wx*16 + c;
        #pragma unroll
        for (int rs = 0; rs < 2; ++rs)
            #pragma unroll
            for (int i = 0; i < 4; ++i) {
                int rloc = wy*32 + rs*16 + q*4 + i;
                #pragma unroll
                for (int j = 0; j < 3; ++j)
                    mpool[rloc*97 + slot*3 + j] = tvp[rs*4 + i][j];
            }
    }
    __syncthreads();

    double* fval = (double*)(smem + OFF_FVAL);   // [64][9]
    int*    fidx = (int*)(smem + OFF_FIDX);      // [64][9]
    if (tid < 64) {
        unsigned bv[8];
        #pragma unroll
        for (int s = 0; s < 8; ++s) bv[s] = 0;
        for (int s2 = 0; s2 < 96; ++s2)
            ins8p(mpool[tid*97 + s2], bv);
        #pragma unroll
        for (int s = 0; s < 8; ++s) fidx[tid*9 + s] = (int)(bv[s] & 2047u);
    }
    __syncthreads();

    // ---- fp64 refinement: 512 candidates, 2 per thread (raw fp32 x) ----
    const float*  xf = x + (size_t)b * Mdim * FD;
    const double* nb = nrm_d + (size_t)b * Mdim;
    #pragma unroll
    for (int it = 0; it < 2; ++it) {
        int id = tid + it * 256;
        int r = id >> 3, sl = id & 7;
        int n = fidx[r*9 + sl];
        int m = row0 + r;
        const f32x4* pm = (const f32x4*)(xf + (size_t)m * FD);
        const f32x4* pn = (const f32x4*)(xf + (size_t)n * FD);
        double a0 = 0.0, a1 = 0.0;
        #pragma unroll 4
        for (int k4 = 0; k4 < FD/4; k4 += 2) {
            f32x4 u0 = pm[k4],   vv0 = pn[k4];
            f32x4 u1 = pm[k4+1], vv1 = pn[k4+1];
            a0 = fma((double)u0[0], (double)vv0[0], a0);
            a0 = fma((double)u0[1], (double)vv0[1], a0);
            a0 = fma((double)u0[2], (double)vv0[2], a0);
            a0 = fma((double)u0[3], (double)vv0[3], a0);
            a1 = fma((double)u1[0], (double)vv1[0], a1);
            a1 = fma((double)u1[1], (double)vv1[1], a1);
            a1 = fma((double)u1[2], (double)vv1[2], a1);
            a1 = fma((double)u1[3], (double)vv1[3], a1);
        }
        fval[r*9 + sl] = (a0 + a1) / (nb[m] * nb[n]);
    }
    __syncthreads();

    // ---- exact top-2 (skip diag by index) + publish + own-row point writes ----
    if (tid < 64) {
        int m = row0 + tid;
        double bv1 = -1e300, bv2 = -1e300; int bi1 = -1, bi2 = -1;
        #pragma unroll
        for (int cc = 0; cc < 8; ++cc) {
            double v = fval[tid*9 + cc];
            int    n = fidx[tid*9 + cc];
            if (n == m) continue;
            if (bi1 < 0 || v > bv1 || (v == bv1 && n < bi1)) {
                bv2 = bv1; bi2 = bi1; bv1 = v; bi1 = n;
            } else if (bi2 < 0 || v > bv2 || (v == bv2 && n < bi2)) {
                bv2 = v; bi2 = n;
            }
        }
        // reference top_k competes against the zeroed diagonal (value 0):
        // val1 always scatters; val2 only if it beats the diagonal zero.
        int  i2w = (bv2 > 0.0) ? bi2 : -1;
        int2   si = make_int2(bi1, i2w);
        float2 sv = make_float2((float)(0.5 * bv1), (float)(0.5 * bv2));
        tops_i[(size_t)b * Mdim + m] = si;
        tops_v[(size_t)b * Mdim + m] = sv;
        size_t obase = (size_t)b * Mdim * Mdim + (size_t)m * Mdim;
        out[obase + si.x] = sv.x;
        if (si.y >= 0) out[obase + si.y] = sv.y;
    }
}

// ---------- Kernel 3: transpose contributions (unique-writer, non-atomic) ----------
__global__ void transpose_kernel(const int2* __restrict__ tops_i,
                                 const float2* __restrict__ tops_v,
                                 float* out) {
    int id = blockIdx.x * 256 + threadIdx.x;
    int b = id >> 11, m = id & (Mdim - 1);
    int2 si = tops_i[id]; float2 sv = tops_v[id];
    float* ob = out + (size_t)b * Mdim * Mdim;
    float* p1 = ob + (size_t)si.x * Mdim + m;
    *p1 += sv.x;
    if (si.y >= 0) {
        float* p2 = ob + (size_t)si.y * Mdim + m;
        *p2 += sv.y;
    }
}

extern "C" void kernel_launch(void* const* d_in, const int* in_sizes, int n_in,
                              void* d_out, int out_size, void* d_ws, size_t ws_size,
                              hipStream_t stream) {
    const float* x = (const float*)d_in[0];
    float* out = (float*)d_out;
    int Bn = in_sizes[0] / (Mdim * FD);   // 16

    char* ws = (char*)d_ws;
    double*         nrm_d  = (double*)ws;
    unsigned short* xnb    = (unsigned short*)(ws + 262144);
    int2*           tops_i = (int2*)(ws + 262144 + 8388608);
    float2*         tops_v = (float2*)(ws + 262144 + 8388608 + 262144);

    prep_kernel<<<Bn * Mdim / 4, 256, 0, stream>>>(x, nrm_d, xnb);
    topk_kernel<<<Bn * 32, 256, 0, stream>>>(x, xnb, nrm_d, out, tops_i, tops_v);
    transpose_kernel<<<Bn * Mdim / 256, 256, 0, stream>>>(tops_i, tops_v, out);
}